// Round 1
// baseline (343.706 us; speedup 1.0000x reference)
//
#include <hip/hip_runtime.h>

// Problem constants (from reference)
#define IN_FEATURES 4096
#define RANK 64
#define NUM_EXPERTS 8
#define KDIM 512          // NUM_EXPERTS * RANK (GEMM K)
#define TOKENS 16384      // B*S = 4*4096      (GEMM M)
#define SCALING 1.0f      // ALPHA / RANK = 64/64

// 256x256 8-phase GEMM (m201-style schedule, plain HIP)
#define BM 256
#define BN 256
#define BK 64
#define NKT (KDIM / BK)   // 8 K-tiles
#define NIT (NKT / 2)     // 4 iterations, 2 K-tiles each

typedef __bf16 bf16x8 __attribute__((ext_vector_type(8)));
typedef float f32x4 __attribute__((ext_vector_type(4)));

__device__ __forceinline__ unsigned short f2bf(float f) {
  union { float f; unsigned int u; } v; v.f = f;
  unsigned int u = v.u;
  u += 0x7fffu + ((u >> 16) & 1u);   // round-to-nearest-even
  return (unsigned short)(u >> 16);
}

__device__ __forceinline__ void gload_lds16(const unsigned short* g, unsigned short* l) {
  __builtin_amdgcn_global_load_lds(
      (const __attribute__((address_space(1))) void*)g,
      (__attribute__((address_space(3))) void*)l,
      16, 0, 0);
}

// q[t, k*RANK+r] = bf16(w[t,k] * p[t,r])   -- [TOKENS, KDIM] bf16
__global__ void __launch_bounds__(256) q_pack(const float* __restrict__ p,
                                              const float* __restrict__ w,
                                              unsigned short* __restrict__ q) {
  int t = blockIdx.x;            // token
  int i = threadIdx.x;           // pair index 0..255 (512 elems / 2)
  int k = i >> 5;                // expert
  int rp = (i & 31) * 2;         // rank pair base
  float wk = w[t * NUM_EXPERTS + k];
  float p0 = p[t * RANK + rp];
  float p1 = p[t * RANK + rp + 1];
  ushort2 o;
  o.x = f2bf(wk * p0);
  o.y = f2bf(wk * p1);
  *(ushort2*)&q[t * KDIM + k * RANK + rp] = o;
}

// Bt[d, k*RANK+r] = bf16(A[k,d,r] * mask[k,d,r] * SCALING)  -- [IN_FEATURES, KDIM] bf16
__global__ void __launch_bounds__(256) b_pack(const float* __restrict__ A,
                                              const float* __restrict__ mask,
                                              unsigned short* __restrict__ Bt) {
  int d = blockIdx.x;
  int i = threadIdx.x;
  int k = i >> 5;
  int rp = (i & 31) * 2;
  long src = ((long)k * IN_FEATURES + d) * RANK + rp;
  float a0 = A[src] * mask[src] * SCALING;
  float a1 = A[src + 1] * mask[src + 1] * SCALING;
  ushort2 o;
  o.x = f2bf(a0);
  o.y = f2bf(a1);
  *(ushort2*)&Bt[d * KDIM + k * RANK + rp] = o;
}

// C[M,N] = q[M,K] @ Bt[N,K]^T. 256x256 tile, BK=64, 8 waves (2M x 4N),
// per-wave 128x64 output = acc[8][4] f32x4. 8-phase schedule, 2 K-tiles/iter:
//   phase p: {ds_read changed fragments; stage 1 half-tile via global_load_lds;
//             sched_barrier; s_barrier; setprio(1); 16 MFMA; setprio(0);
//             sched_barrier; s_barrier}
// Counted vmcnt(4) only at phases 4/8 (2 half-tiles x 2 loads stay in flight).
// Half-tile stage order (global phase 4t+3..4t+6): B0,B1,A0,A1 of K-tile t+2;
// every LDS slot is overwritten >=1 barrier-pair after its last ds_read.
// LDS chunk swizzle (both sides): chunk c -> linear LDS byte c*16; row=c>>3,
// logical k-chunk = (c&7)^(row&7); read back with phys = kc ^ (row&7).
__global__ void __launch_bounds__(512, 2) gemm_kernel(
    const unsigned short* __restrict__ q,   // [TOKENS, KDIM]
    const unsigned short* __restrict__ Bt,  // [IN_FEATURES, KDIM]
    float* __restrict__ out) {              // [TOKENS, IN_FEATURES]
  __shared__ __align__(16) unsigned short sA[2][2][128 * BK];  // 64 KiB
  __shared__ __align__(16) unsigned short sB[2][2][128 * BK];  // 64 KiB

  const int tid = threadIdx.x;
  const int lane = tid & 63;
  const int wid = tid >> 6;
  const int u = lane & 15;        // fragment row-within-16
  const int quad = lane >> 4;     // k-quad / output row group
  const int hA = wid >> 2;        // which A staging half this wave reads
  const int hB = (wid & 3) >> 1;  // which B staging half
  const int rB = (wid & 1) * 64;  // row base within B half
  const int wn = (wid & 3) * 64;  // col base within block tile

  const int m0 = blockIdx.y * BM;
  const int n0 = blockIdx.x * BN;

  f32x4 acc[8][4];
#pragma unroll
  for (int i = 0; i < 8; ++i)
#pragma unroll
    for (int j = 0; j < 4; ++j)
      acc[i][j] = (f32x4){0.f, 0.f, 0.f, 0.f};

  // Staging addresses: each thread stages chunks c0=tid, c1=tid+512 of a
  // 128x64 half-tile (1024 x 16B chunks). LDS dest linear; global src swizzled.
  const int c0 = tid, c1 = tid + 512;
  const int row0 = c0 >> 3, row1 = c1 >> 3;
  const int log0 = (c0 & 7) ^ (row0 & 7), log1 = (c1 & 7) ^ (row1 & 7);
  const unsigned short* gA0 = q + (m0 + row0) * KDIM + log0 * 8;
  const unsigned short* gA1 = q + (m0 + row1) * KDIM + log1 * 8;
  const unsigned short* gB0 = Bt + (n0 + row0) * KDIM + log0 * 8;
  const unsigned short* gB1 = Bt + (n0 + row1) * KDIM + log1 * 8;
  const int l0 = c0 * 8, l1 = c1 * 8;

  auto stageA = [&](int buf, int h, int kt) {
    int ko = (kt & (NKT - 1)) * BK + h * 128 * KDIM;
    gload_lds16(gA0 + ko, &sA[buf][h][l0]);
    gload_lds16(gA1 + ko, &sA[buf][h][l1]);
  };
  auto stageB = [&](int buf, int h, int kt) {
    int ko = (kt & (NKT - 1)) * BK + h * 128 * KDIM;
    gload_lds16(gB0 + ko, &sB[buf][h][l0]);
    gload_lds16(gB1 + ko, &sB[buf][h][l1]);
  };

  auto ldA = [&](int buf, int mq, bf16x8 (&a)[2][4]) {
    const unsigned short* base = sA[buf][hA];
#pragma unroll
    for (int ki = 0; ki < 2; ++ki)
#pragma unroll
      for (int f = 0; f < 4; ++f) {
        int r = mq * 64 + f * 16 + u;
        int phys = (ki * 4 + quad) ^ (r & 7);
        a[ki][f] = *(const bf16x8*)&base[r * BK + phys * 8];
      }
  };
  auto ldB = [&](int buf, int nq, bf16x8 (&b)[2][2]) {
    const unsigned short* base = sB[buf][hB];
#pragma unroll
    for (int ki = 0; ki < 2; ++ki)
#pragma unroll
      for (int g = 0; g < 2; ++g) {
        int r = rB + nq * 32 + g * 16 + u;
        int phys = (ki * 4 + quad) ^ (r & 7);
        b[ki][g] = *(const bf16x8*)&base[r * BK + phys * 8];
      }
  };
  auto mfmaQ = [&](int mq, int nq, bf16x8 (&a)[2][4], bf16x8 (&b)[2][2]) {
    __builtin_amdgcn_s_setprio(1);
#pragma unroll
    for (int ki = 0; ki < 2; ++ki)
#pragma unroll
      for (int f = 0; f < 4; ++f)
#pragma unroll
        for (int g = 0; g < 2; ++g)
          acc[mq * 4 + f][nq * 2 + g] = __builtin_amdgcn_mfma_f32_16x16x32_bf16(
              a[ki][f], b[ki][g], acc[mq * 4 + f][nq * 2 + g], 0, 0, 0);
    __builtin_amdgcn_s_setprio(0);
  };
  auto phase_bar = [&]() {
    __builtin_amdgcn_sched_barrier(0);
    __builtin_amdgcn_s_barrier();
  };

  bf16x8 Ar[2][4], B0r[2][2], B1r[2][2];

  // Prologue: emulate steady-state issue order B0,B1,A0,A1(kt0), B0,B1(kt1).
  stageB(0, 0, 0); stageB(0, 1, 0);
  stageA(0, 0, 0); stageA(0, 1, 0);
  stageB(1, 0, 1); stageB(1, 1, 1);
  asm volatile("s_waitcnt vmcnt(4)" ::: "memory");  // kt0 resident; B(kt1) in flight
  phase_bar();

  for (int i = 0; i < NIT; ++i) {
    const int k1 = 2 * i + 1, k2 = 2 * i + 2, k3 = 2 * i + 3;
    // ph1: kt=2i quadrant (mq0,nq0); stage A0(kt+1)->buf1
    ldA(0, 0, Ar); ldB(0, 0, B0r);
    stageA(1, 0, k1);
    phase_bar();
    mfmaQ(0, 0, Ar, B0r);
    phase_bar();
    // ph2: (mq0,nq1); stage A1(kt+1)->buf1
    ldB(0, 1, B1r);
    stageA(1, 1, k1);
    phase_bar();
    mfmaQ(0, 1, Ar, B1r);
    phase_bar();
    // ph3: (mq1,nq1); stage B0(kt+2)->buf0
    ldA(0, 1, Ar);
    stageB(0, 0, k2);
    phase_bar();
    mfmaQ(1, 1, Ar, B1r);
    phase_bar();
    // ph4: (mq1,nq0) from regs; stage B1(kt+2)->buf0; counted wait for kt+1
    stageB(0, 1, k2);
    phase_bar();
    mfmaQ(1, 0, Ar, B0r);
    asm volatile("s_waitcnt vmcnt(4)" ::: "memory");
    phase_bar();
    // ph5: kt=2i+1 (mq0,nq0); stage A0(kt+2)->buf0
    ldA(1, 0, Ar); ldB(1, 0, B0r);
    stageA(0, 0, k2);
    phase_bar();
    mfmaQ(0, 0, Ar, B0r);
    phase_bar();
    // ph6: (mq0,nq1); stage A1(kt+2)->buf0
    ldB(1, 1, B1r);
    stageA(0, 1, k2);
    phase_bar();
    mfmaQ(0, 1, Ar, B1r);
    phase_bar();
    // ph7: (mq1,nq1); stage B0(kt+3)->buf1
    ldA(1, 1, Ar);
    stageB(1, 0, k3);
    phase_bar();
    mfmaQ(1, 1, Ar, B1r);
    phase_bar();
    // ph8: (mq1,nq0) from regs; stage B1(kt+3)->buf1; counted wait for kt+2
    stageB(1, 1, k3);
    phase_bar();
    mfmaQ(1, 0, Ar, B0r);
    asm volatile("s_waitcnt vmcnt(4)" ::: "memory");
    phase_bar();
  }

  // Epilogue: C/D layout col = lane&15, row = quad*4 + reg
#pragma unroll
  for (int mf = 0; mf < 8; ++mf) {
    int row = m0 + hA * 128 + mf * 16 + quad * 4;
#pragma unroll
    for (int rr = 0; rr < 4; ++rr) {
      float* orow = out + (long)(row + rr) * IN_FEATURES + n0 + wn + u;
#pragma unroll
      for (int nf = 0; nf < 4; ++nf)
        orow[nf * 16] = acc[mf][nf][rr];
    }
  }
}

extern "C" void kernel_launch(void* const* d_in, const int* in_sizes, int n_in,
                              void* d_out, int out_size, void* d_ws, size_t ws_size,
                              hipStream_t stream) {
  const float* p    = (const float*)d_in[0];  // [4,4096,64]
  const float* w    = (const float*)d_in[1];  // [4,4096,8]
  const float* A    = (const float*)d_in[2];  // [8,4096,64]
  const float* mask = (const float*)d_in[3];  // [8,4096,64]
  float* out = (float*)d_out;                 // [4,4096,4096]

  unsigned short* q  = (unsigned short*)d_ws;            // 16 MiB bf16 [TOKENS, KDIM]
  unsigned short* Bt = q + (size_t)TOKENS * KDIM;        //  4 MiB bf16 [IN_FEATURES, KDIM]

  q_pack<<<TOKENS, 256, 0, stream>>>(p, w, q);
  b_pack<<<IN_FEATURES, 256, 0, stream>>>(A, mask, Bt);

  dim3 grid(IN_FEATURES / BN, TOKENS / BM);
  gemm_kernel<<<grid, dim3(512), 0, stream>>>(q, Bt, out);
}